// Round 10
// baseline (296.127 us; speedup 1.0000x reference)
//
#include <hip/hip_runtime.h>
#include <hip/hip_bf16.h>
#include <stdint.h>

#define NROWS 131072
#define LMD   1024
#define GNND  200
#define HD    128
#define BLOCK 256
#define MTILE 64
#define GRID  512              // persistent: 2 blocks/CU exactly
#define NTILE 4                // 4 row-tiles per block
#define WCH   16384            // W chunk bytes (128 h x 64 k bf16)

typedef __attribute__((ext_vector_type(4))) float  f32x4;
typedef __attribute__((ext_vector_type(8))) short  bf16x8;

#define GLDS(SRC, DST) __builtin_amdgcn_global_load_lds( \
    (const __attribute__((address_space(1))) unsigned int*)(SRC), \
    (__attribute__((address_space(3))) unsigned int*)(DST), 16, 0, 0)
#define SCHED0  __builtin_amdgcn_sched_barrier(0)
#define BAR     __builtin_amdgcn_s_barrier()
#define VMW(N)  asm volatile("s_waitcnt vmcnt(" #N ")" ::: "memory")

__device__ __forceinline__ short f2bf(float x) {
    union { __hip_bfloat16 h; short s; } u;
    u.h = __float2bfloat16(x);
    return u.s;
}

__device__ __forceinline__ bf16x8 cvt8(f32x4 a, f32x4 b) {
    bf16x8 r;
    r[0]=f2bf(a[0]); r[1]=f2bf(a[1]); r[2]=f2bf(a[2]); r[3]=f2bf(a[3]);
    r[4]=f2bf(b[0]); r[5]=f2bf(b[1]); r[6]=f2bf(b[2]); r[7]=f2bf(b[3]);
    return r;
}

__device__ __forceinline__ float red16(float v) {
    #pragma unroll
    for (int m=1; m<16; m<<=1) v += __shfl_xor(v, m, 16);
    return v;
}

// ---- prep: K=64 chunk-major, swizzle-baked W panels ----
// W1S[ch][row][e] = bf16(lm_W[kk][row]), kk = ch*64 + (e ^ ((row&7)*8))
__global__ void prep_weights(const float* __restrict__ lm_W,
                             const float* __restrict__ gnn_W,
                             short* __restrict__ W1S, short* __restrict__ W2S)
{
    int idx = blockIdx.x*BLOCK + threadIdx.x;     // 512*256 = 131072 = 16 chunks * 8192 shorts
    int row = (idx >> 6) & 127;
    int e   = idx & 63;
    int kk  = (idx >> 13)*64 + (e ^ ((row & 7)*8));
    W1S[idx] = f2bf(lm_W[(long)kk*HD + row]);
    if (idx < 4*8192) {
        W2S[idx] = (kk < GNND) ? f2bf(gnn_W[(long)kk*HD + row]) : (short)0;
    }
}

__global__ __launch_bounds__(BLOCK, 2) void fused(
    const float* __restrict__ lm,  const float* __restrict__ gnn,
    const float* __restrict__ ngn,
    const float* __restrict__ lm_b, const float* __restrict__ gnn_b,
    const char* __restrict__ W1S,  const char* __restrict__ W2S,
    float* __restrict__ partials)
{
    __shared__ short lbuf[4*8192];      // 64 KB: W bufs b0..b3 (pairs {0,1},{2,3})
    __shared__ float sp[4], sn[4];

    const int tid  = threadIdx.x;
    const int lane = tid & 63;
    const int win  = tid >> 6;
    const int col  = lane & 15;
    const int g    = lane >> 4;
    const int wq   = win*4096 + lane*16;           // wave's staging quarter

    const long rowoff = (long)((long)blockIdx.x*MTILE + win*16 + col);
    const long TSL = (long)GRID*MTILE*(LMD*4L);    // tile stride, lm bytes
    const long TSG = (long)GRID*MTILE*(GNND*4L);   // tile stride, gnn bytes

    const char* aL = (const char*)lm  + rowoff*(LMD*4L)  + g*32;
    const char* aG = (const char*)gnn + rowoff*(GNND*4L) + g*32;
    const char* aN = (const char*)ngn + rowoff*(GNND*4L) + g*32;
    const char* clampG = (const char*)gnn + (size_t)NROWS*GNND*4 - 16;
    const char* clampN = (const char*)ngn + (size_t)NROWS*GNND*4 - 16;

    const float CC   = 1.0f / 11008.0f;
    const float LOGC = -9.3063777f;                // log(1/11008)
    const f32x4 fz = {0.f,0.f,0.f,0.f};

    // stage one W chunk into buf b
    auto ISSUEW = [&](const char* ws, int b) {
        const char* s = ws + wq;
        char* d = (char*)lbuf + (size_t)b*WCH + wq;
        #pragma unroll
        for (int i=0;i<4;i++) GLDS(s + i*1024, d + i*1024);
    };
    // load one K=128 A-group (512B per row, 8 x dwordx4 per lane)
    auto LOADG = [&](const char* base, int off, const char* cl, f32x4 (&S)[8]) {
        #pragma unroll
        for (int j=0;j<4;j++) {
            const char* p0 = base + off + j*128;
            const char* p1 = p0 + 16;
            if (cl) { if (p0 > cl) p0 = cl;  if (p1 > cl) p1 = cl; }
            S[2*j]   = *(const f32x4*)p0;
            S[2*j+1] = *(const f32x4*)p1;
        }
    };

    f32x4 SA[8], SB[8];
    f32x4 accL[8], accG[8];
    float pos_acc = 0.f, neg_acc = 0.f;

    // one K=64 chunk of MFMA: W from buf c&3, A set by (c>>1)&1, half c&1
    auto COMP = [&](int c, f32x4 (&acc)[8]) {
        const short* wb = lbuf + (c & 3)*8192 + col*64;
        const int sw = (col & 7)*8;
        f32x4 (&S)[8] = ((c>>1)&1) ? SB : SA;
        const int half = c & 1;
        #pragma unroll
        for (int ks=0; ks<2; ++ks) {
            bf16x8 af = cvt8(S[half*4 + 2*ks], S[half*4 + 2*ks + 1]);
            const short* cb = wb + ((ks*32 + g*8) ^ sw);
            #pragma unroll
            for (int t=0;t<8;t++) {
                bf16x8 wf = *(const bf16x8*)(cb + t*1024);
                acc[t] = __builtin_amdgcn_mfma_f32_16x16x32_bf16(af, wf, acc[t], 0,0,0);
            }
        }
    };
    // W-pair source consumed at super S (per tile)
    auto WPAIR = [&](int S)->const char* {
        if (S < 8)  return W1S + (size_t)(2*S)*WCH;
        return (S & 1) ? (W2S + 2*WCH) : W2S;      // S=8,10 -> W2{0,1}; S=9,11 -> W2{2,3}
    };

    // ---- biases first (drained at first wait, FIFO stays pure afterwards) ----
    float bl[8], bg[8];
    #pragma unroll
    for (int t=0;t<8;t++) bl[t] = lm_b[t*16+col];
    #pragma unroll
    for (int t=0;t<8;t++) bg[t] = gnn_b[t*16+col];
    SCHED0;

    // ---- prologue (tile 0): [Wpair0][A0][Wpair1][A1], retain Wpair1+A1 ----
    ISSUEW(W1S,        0);
    ISSUEW(W1S + WCH,  1);
    LOADG(aL, 0, nullptr, SA);
    SCHED0;
    ISSUEW(W1S + 2*WCH, 2);
    ISSUEW(W1S + 3*WCH, 3);
    LOADG(aL, 512, nullptr, SB);
    SCHED0; VMW(16); SCHED0; BAR; SCHED0;
    #pragma unroll
    for (int t=0;t<8;t++) { asm volatile("" : "+v"(bl[t])); asm volatile("" : "+v"(bg[t])); }

    #pragma unroll 1
    for (int t4 = 0; t4 < NTILE; ++t4) {
        const bool last = (t4 == NTILE-1);

        #pragma unroll
        for (int t=0;t<8;t++) accL[t] = fz;

        // ---- supers 0..6 (lm): Wpair(S+1), 2 COMPs, A(S+2), vmw8 ----
        #pragma unroll
        for (int S = 0; S < 7; ++S) {
            const char* wp = WPAIR(S+1);
            ISSUEW(wp,       ((S+1)&1)*2    );
            ISSUEW(wp + WCH, ((S+1)&1)*2 + 1);
            SCHED0;
            COMP(2*S,   accL);
            COMP(2*S+1, accL);
            SCHED0;
            if (S < 6) LOADG(aL, (S+2)*512, nullptr, (S&1) ? SB : SA);
            else       LOADG(aG, 0, clampG, SA);                 // group 8
            SCHED0; VMW(8); SCHED0; BAR; SCHED0;
        }
        // ---- super 7 (lm tail): Wpair(8)=W2{0,1}->pair0, A(9)=gnn512 ----
        ISSUEW(W2S,       0);
        ISSUEW(W2S + WCH, 1);
        SCHED0;
        COMP(14, accL);
        COMP(15, accL);
        SCHED0;
        LOADG(aG, 512, clampG, SB);                              // group 9
        SCHED0; VMW(8); SCHED0; BAR; SCHED0;

        // lm bias + accG reset (VALU, overlaps in-flight loads)
        #pragma unroll
        for (int t=0;t<8;t++) {
            #pragma unroll
            for (int r=0;r<4;r++) accL[t][r] += bl[t];
        }
        #pragma unroll
        for (int t=0;t<8;t++) accG[t] = fz;

        // ---- super 8 (pos): Wpair(9)=W2{2,3}->pair1, A(10)=ngn0 ----
        ISSUEW(W2S + 2*WCH, 2);
        ISSUEW(W2S + 3*WCH, 3);
        SCHED0;
        COMP(16, accG);
        COMP(17, accG);
        SCHED0;
        LOADG(aN, 0, clampN, SA);                                // group 10
        SCHED0; VMW(8); SCHED0; BAR; SCHED0;

        // ---- super 9 (pos): no W, A(11)=ngn512 ----
        COMP(18, accG);
        COMP(19, accG);
        SCHED0;
        LOADG(aN, 512, clampN, SB);                              // group 11
        SCHED0; VMW(8); SCHED0; BAR; SCHED0;

        // ---- pos epilogue ----
        #pragma unroll
        for (int r=0;r<4;r++) {
            float lg=0.f, ll=0.f, gg2=0.f;
            #pragma unroll
            for (int t=0;t<8;t++) {
                float lv=accL[t][r], gv=accG[t][r]+bg[t];
                lg += lv*gv; ll += lv*lv; gg2 += gv*gv;
            }
            lg=red16(lg); ll=red16(ll); gg2=red16(gg2);
            float d  = lg * rsqrtf(ll*gg2);
            float pi = d - logf(expf(d)+CC);     // log(ratio)
            if (col==0) pos_acc += pi;
        }
        #pragma unroll
        for (int t=0;t<8;t++) accG[t] = fz;

        // ---- super 10 (neg): W2{0,1} resident in pair0; next-tile A(0) ----
        COMP(20, accG);
        COMP(21, accG);
        SCHED0;
        if (!last) {
            LOADG(aL + TSL, 0, nullptr, SA);                     // next tile group 0
            SCHED0; VMW(8); SCHED0; BAR; SCHED0;
        } else {
            SCHED0; VMW(0); SCHED0; BAR; SCHED0;
        }

        // ---- super 11 (neg): W2{2,3} resident in pair1; next-tile W1{0,1}+A(1) ----
        if (!last) {
            ISSUEW(W1S,       0);
            ISSUEW(W1S + WCH, 1);
            SCHED0;
        }
        COMP(22, accG);
        COMP(23, accG);
        SCHED0;
        if (!last) {
            LOADG(aL + TSL, 512, nullptr, SB);                   // next tile group 1
            SCHED0; VMW(8); SCHED0; BAR; SCHED0;
        }

        // ---- neg epilogue ----
        #pragma unroll
        for (int r=0;r<4;r++) {
            float ln=0.f, nn=0.f, ll=0.f;
            #pragma unroll
            for (int t=0;t<8;t++) {
                float lv=accL[t][r], nv=accG[t][r]+bg[t];
                ln += lv*nv; nn += nv*nv; ll += lv*lv;
            }
            ln=red16(ln); nn=red16(nn); ll=red16(ll);
            float d  = ln * rsqrtf(ll*nn);
            float ni = LOGC - logf(expf(d)+CC);  // log(1-ratio)
            if (col==0) neg_acc += ni;
        }

        // advance tile bases
        aL += TSL; aG += TSG; aN += TSG;
    }

    // ---- wave + block reduce: one partials entry per block ----
    #pragma unroll
    for (int m=1;m<64;m<<=1) {
        pos_acc += __shfl_xor(pos_acc, m, 64);
        neg_acc += __shfl_xor(neg_acc, m, 64);
    }
    if (lane==0) { sp[win]=pos_acc; sn[win]=neg_acc; }
    __syncthreads();
    if (tid==0) {
        float p=0.f,n=0.f;
        #pragma unroll
        for (int w=0;w<4;w++){ p+=sp[w]; n+=sn[w]; }
        partials[blockIdx.x*2]   = p;
        partials[blockIdx.x*2+1] = n;
    }
}

__global__ void finalize(const float* __restrict__ partials, float* __restrict__ out)
{
    __shared__ float sp[BLOCK], sn[BLOCK];
    float p=0.f, n=0.f;
    for (int i=threadIdx.x; i<GRID; i+=BLOCK) { p += partials[2*i]; n += partials[2*i+1]; }
    sp[threadIdx.x]=p; sn[threadIdx.x]=n;
    __syncthreads();
    for (int s=BLOCK/2; s>0; s>>=1) {
        if (threadIdx.x < s) { sp[threadIdx.x]+=sp[threadIdx.x+s]; sn[threadIdx.x]+=sn[threadIdx.x+s]; }
        __syncthreads();
    }
    if (threadIdx.x==0) out[0] = -(sp[0]+sn[0]) / (float)NROWS;
}

extern "C" void kernel_launch(void* const* d_in, const int* in_sizes, int n_in,
                              void* d_out, int out_size, void* d_ws, size_t ws_size,
                              hipStream_t stream)
{
    const float* lm    = (const float*)d_in[0];
    const float* gnn   = (const float*)d_in[1];
    const float* ngn   = (const float*)d_in[2];
    const float* lm_W  = (const float*)d_in[3];
    const float* lm_b  = (const float*)d_in[4];
    const float* gnn_W = (const float*)d_in[5];
    const float* gnn_b = (const float*)d_in[6];

    short* W1S = (short*)d_ws;                                   // 16*16384 = 262144 B
    short* W2S = (short*)((char*)d_ws + 262144);                 //  4*16384 =  65536 B
    float* partials = (float*)((char*)d_ws + 262144 + 65536);    // 4 KB

    prep_weights<<<512, BLOCK, 0, stream>>>(lm_W, gnn_W, W1S, W2S);
    fused<<<GRID, BLOCK, 0, stream>>>(lm, gnn, ngn, lm_b, gnn_b,
                                      (const char*)W1S, (const char*)W2S, partials);
    finalize<<<1, BLOCK, 0, stream>>>(partials, (float*)d_out);
}

// Round 11
// 214.079 us; speedup vs baseline: 1.3833x; 1.3833x over previous
//
#include <hip/hip_runtime.h>
#include <hip/hip_bf16.h>
#include <stdint.h>

#define NROWS 131072
#define LMD   1024
#define GNND  200
#define HD    128
#define BLOCK 512
#define GRID  256
#define NTILE 4
#define MTILE 128
#define ACH   32768              // A chunk bytes: 128 rows x 64 k f32
#define WCH   16384              // W chunk bytes: 128 h x 64 k bf16
#define LDS_W0 (3*ACH)           // W bufs after 3 A bufs
#define LDS_TOT (3*ACH + 2*WCH)  // 131072

typedef __attribute__((ext_vector_type(4))) float  f32x4;
typedef __attribute__((ext_vector_type(8))) short  bf16x8;

#define GLDS(SRC, DST) __builtin_amdgcn_global_load_lds( \
    (const __attribute__((address_space(1))) unsigned int*)(SRC), \
    (__attribute__((address_space(3))) unsigned int*)(DST), 16, 0, 0)
#define SCHED0  __builtin_amdgcn_sched_barrier(0)
#define BAR     __builtin_amdgcn_s_barrier()
#define VMW(N)  asm volatile("s_waitcnt vmcnt(" #N ")" ::: "memory")

__device__ __forceinline__ short f2bf(float x) {
    union { __hip_bfloat16 h; short s; } u;
    u.h = __float2bfloat16(x);
    return u.s;
}

__device__ __forceinline__ bf16x8 cvt8(f32x4 a, f32x4 b) {
    bf16x8 r;
    r[0]=f2bf(a[0]); r[1]=f2bf(a[1]); r[2]=f2bf(a[2]); r[3]=f2bf(a[3]);
    r[4]=f2bf(b[0]); r[5]=f2bf(b[1]); r[6]=f2bf(b[2]); r[7]=f2bf(b[3]);
    return r;
}

__device__ __forceinline__ float red16(float v) {
    #pragma unroll
    for (int m=1; m<16; m<<=1) v += __shfl_xor(v, m, 16);
    return v;
}

// ---- prep: K=64 chunk-major, swizzle-baked W panels (unchanged, proven) ----
__global__ void prep_weights(const float* __restrict__ lm_W,
                             const float* __restrict__ gnn_W,
                             short* __restrict__ W1S, short* __restrict__ W2S)
{
    int idx = blockIdx.x*256 + threadIdx.x;       // 512*256 = 131072 = 16 chunks * 8192 shorts
    int row = (idx >> 6) & 127;
    int e   = idx & 63;
    int kk  = (idx >> 13)*64 + (e ^ ((row & 7)*8));
    W1S[idx] = f2bf(lm_W[(long)kk*HD + row]);
    if (idx < 4*8192) {
        W2S[idx] = (kk < GNND) ? f2bf(gnn_W[(long)kk*HD + row]) : (short)0;
    }
}

__global__ __launch_bounds__(BLOCK, 2) void fused(
    const float* __restrict__ lm,  const float* __restrict__ gnn,
    const float* __restrict__ ngn,
    const float* __restrict__ lm_b, const float* __restrict__ gnn_b,
    const char* __restrict__ W1S,  const char* __restrict__ W2S,
    float* __restrict__ partials)
{
    extern __shared__ char lbuf[];               // 128 KB dynamic

    const int tid  = threadIdx.x;
    const int lane = tid & 63;
    const int win  = tid >> 6;                   // 0..7
    const int col  = lane & 15;
    const int g    = lane >> 4;

    const long R0  = (long)blockIdx.x * MTILE;
    const long TSL = (long)GRID*MTILE*(LMD*4L);
    const long TSG = (long)GRID*MTILE*(GNND*4L);

    const char* aLb = (const char*)lm  + R0*(LMD*4L);
    const char* aGb = (const char*)gnn + R0*(GNND*4L);
    const char* aNb = (const char*)ngn + R0*(GNND*4L);
    const char* clampG = (const char*)gnn + (size_t)NROWS*GNND*4 - 16;
    const char* clampN = (const char*)ngn + (size_t)NROWS*GNND*4 - 16;

    const float CC   = 1.0f / 11008.0f;
    const float LOGC = -9.3063777f;              // log(1/11008)
    const f32x4 fz = {0.f,0.f,0.f,0.f};

    // ---- biases (queue-drained at prologue wait) ----
    float bl[8], bg[8];
    #pragma unroll
    for (int t=0;t<8;t++) bl[t] = lm_b[t*16+col];
    #pragma unroll
    for (int t=0;t<8;t++) bg[t] = gnn_b[t*16+col];
    SCHED0;

    // stage W chunk x -> wbuf[x&1] (2 GLDS/thread)
    auto STAGEW = [&](int x) {
        const char* ws = (x < 16) ? W1S + (size_t)x*WCH
                       : (x < 20) ? W2S + (size_t)(x-16)*WCH
                       : (x < 24) ? W2S + (size_t)(x-20)*WCH
                                  : W1S;                       // x==24: next tile chunk 0
        char* wd = lbuf + LDS_W0 + (size_t)(x & 1)*WCH;
        #pragma unroll
        for (int i=0;i<2;i++) {
            int u = i*BLOCK + tid;
            GLDS(ws + u*16, wd + u*16);
        }
    };

    // stage A chunk x -> abuf[x%3] (4 GLDS/thread, source swizzle-baked seg^(row&7))
    auto STAGEA = [&](int x) {
        const char* base; long rowB; const char* cl;
        if (x >= 24)     { base = aLb + TSL + (size_t)(x-24)*256; rowB = LMD*4L;  cl = nullptr; }
        else if (x < 16) { base = aLb + (size_t)x*256;            rowB = LMD*4L;  cl = nullptr; }
        else if (x < 20) { base = aGb + (size_t)(x-16)*256;       rowB = GNND*4L; cl = clampG; }
        else             { base = aNb + (size_t)(x-20)*256;       rowB = GNND*4L; cl = clampN; }
        char* ad = lbuf + (size_t)(x % 3)*ACH;
        #pragma unroll
        for (int i=0;i<4;i++) {
            int u  = i*BLOCK + tid;
            int r  = u >> 4;
            int sg = (u & 15) ^ (r & 7);
            const char* src = base + (long)r*rowB + sg*16;
            if (cl && src > cl) src = cl;
            GLDS(src, ad + u*16);
        }
    };

    const int rb = (win*16 + col) * 256;          // A row byte offset
    const int s7 = col & 7;                       // (win*16+col)&7 == col&7
    const int sw = (col & 7) * 8;                 // W swizzle (shorts)

    auto COMP = [&](int c, f32x4 (&acc)[8]) {
        const char*  ab = lbuf + (size_t)(c % 3)*ACH;
        const short* wb = (const short*)(lbuf + LDS_W0 + (size_t)(c & 1)*WCH) + col*64;
        #pragma unroll
        for (int ks=0; ks<2; ++ks) {
            const int u0 = ks*8 + g*2;
            f32x4 a0 = *(const f32x4*)(ab + rb + (((u0    ) ^ s7) << 4));
            f32x4 a1 = *(const f32x4*)(ab + rb + (((u0 + 1) ^ s7) << 4));
            bf16x8 af = cvt8(a0, a1);
            const short* cb = wb + ((ks*32 + g*8) ^ sw);
            #pragma unroll
            for (int t=0;t<8;t++) {
                bf16x8 wf = *(const bf16x8*)(cb + t*1024);
                acc[t] = __builtin_amdgcn_mfma_f32_16x16x32_bf16(af, wf, acc[t], 0,0,0);
            }
        }
    };

    float pos_acc = 0.f, neg_acc = 0.f;

    // ---- prologue: W(0),A(0),W(1),A(1); wait leaves W1+A1 in flight ----
    STAGEW(0); STAGEA(0); STAGEW(1); STAGEA(1);
    SCHED0; VMW(6); SCHED0; BAR; SCHED0;
    #pragma unroll
    for (int t=0;t<8;t++) { asm volatile("" : "+v"(bl[t])); asm volatile("" : "+v"(bg[t])); }

    #pragma unroll 1
    for (int t4 = 0; t4 < NTILE; ++t4) {
        const bool lastT = (t4 == NTILE-1);
        f32x4 accL[8], accG[8];
        #pragma unroll
        for (int t=0;t<8;t++) accL[t] = fz;

        // ---- lm: chunks 0..15 ----
        #pragma unroll
        for (int c = 0; c < 16; ++c) {
            if (c > 0 || t4 > 0) STAGEW(c+1);
            STAGEA(c+2);
            SCHED0;
            COMP(c, accL);
            SCHED0; VMW(4); SCHED0; BAR; SCHED0;
        }
        #pragma unroll
        for (int t=0;t<8;t++) {
            #pragma unroll
            for (int r=0;r<4;r++) accL[t][r] += bl[t];
        }
        #pragma unroll
        for (int t=0;t<8;t++) accG[t] = fz;

        // ---- pos: chunks 16..19 ----
        #pragma unroll
        for (int c = 16; c < 20; ++c) {
            STAGEW(c+1);
            STAGEA(c+2);
            SCHED0;
            COMP(c, accG);
            SCHED0; VMW(4); SCHED0; BAR; SCHED0;
        }
        // pos epilogue
        #pragma unroll
        for (int r=0;r<4;r++) {
            float lg=0.f, ll=0.f, gg2=0.f;
            #pragma unroll
            for (int t=0;t<8;t++) {
                float lv=accL[t][r], gv=accG[t][r]+bg[t];
                lg += lv*gv; ll += lv*lv; gg2 += gv*gv;
            }
            lg=red16(lg); ll=red16(ll); gg2=red16(gg2);
            float d  = lg * rsqrtf(ll*gg2);
            float pi = d - logf(expf(d)+CC);     // log(ratio)
            if (col==0) pos_acc += pi;
        }
        #pragma unroll
        for (int t=0;t<8;t++) accG[t] = fz;

        // ---- neg: chunks 20..23 (cross-tile staging at 22/23) ----
        #pragma unroll
        for (int c = 20; c < 24; ++c) {
            if (c < 23 || !lastT) STAGEW(c+1);
            if (c < 22 || !lastT) STAGEA(c+2);
            SCHED0;
            COMP(c, accG);
            SCHED0;
            if (!lastT)          { VMW(4); SCHED0; BAR; SCHED0; }
            else if (c < 22)     { VMW(4); SCHED0; BAR; SCHED0; }
            else if (c == 22)    { VMW(0); SCHED0; BAR; SCHED0; }
            // lastT c==23: nothing outstanding, no barrier needed here
        }
        // neg epilogue
        #pragma unroll
        for (int r=0;r<4;r++) {
            float ln=0.f, nn=0.f, ll=0.f;
            #pragma unroll
            for (int t=0;t<8;t++) {
                float lv=accL[t][r], nv=accG[t][r]+bg[t];
                ln += lv*nv; nn += nv*nv; ll += lv*lv;
            }
            ln=red16(ln); nn=red16(nn); ll=red16(ll);
            float d  = ln * rsqrtf(ll*nn);
            float ni = LOGC - logf(expf(d)+CC);  // log(1-ratio)
            if (col==0) neg_acc += ni;
        }

        aLb += TSL; aGb += TSG; aNb += TSG;
    }

    // ---- wave + block reduce (reuse lbuf after full sync) ----
    #pragma unroll
    for (int m=1;m<64;m<<=1) {
        pos_acc += __shfl_xor(pos_acc, m, 64);
        neg_acc += __shfl_xor(neg_acc, m, 64);
    }
    __syncthreads();                    // all waves done with lbuf
    float* sp = (float*)lbuf;
    float* sn = sp + 8;
    if (lane==0) { sp[win]=pos_acc; sn[win]=neg_acc; }
    __syncthreads();
    if (tid==0) {
        float p=0.f,n=0.f;
        #pragma unroll
        for (int w=0;w<8;w++){ p+=sp[w]; n+=sn[w]; }
        partials[blockIdx.x*2]   = p;
        partials[blockIdx.x*2+1] = n;
    }
}

__global__ void finalize(const float* __restrict__ partials, float* __restrict__ out)
{
    __shared__ float sp[256], sn[256];
    float p=0.f, n=0.f;
    for (int i=threadIdx.x; i<GRID; i+=256) { p += partials[2*i]; n += partials[2*i+1]; }
    sp[threadIdx.x]=p; sn[threadIdx.x]=n;
    __syncthreads();
    for (int s=128; s>0; s>>=1) {
        if ((int)threadIdx.x < s) { sp[threadIdx.x]+=sp[threadIdx.x+s]; sn[threadIdx.x]+=sn[threadIdx.x+s]; }
        __syncthreads();
    }
    if (threadIdx.x==0) out[0] = -(sp[0]+sn[0]) / (float)NROWS;
}

extern "C" void kernel_launch(void* const* d_in, const int* in_sizes, int n_in,
                              void* d_out, int out_size, void* d_ws, size_t ws_size,
                              hipStream_t stream)
{
    const float* lm    = (const float*)d_in[0];
    const float* gnn   = (const float*)d_in[1];
    const float* ngn   = (const float*)d_in[2];
    const float* lm_W  = (const float*)d_in[3];
    const float* lm_b  = (const float*)d_in[4];
    const float* gnn_W = (const float*)d_in[5];
    const float* gnn_b = (const float*)d_in[6];

    short* W1S = (short*)d_ws;                                   // 16*16384 = 262144 B
    short* W2S = (short*)((char*)d_ws + 262144);                 //  4*16384 =  65536 B
    float* partials = (float*)((char*)d_ws + 262144 + 65536);    // 2 KB

    hipFuncSetAttribute((const void*)fused,
                        hipFuncAttributeMaxDynamicSharedMemorySize, LDS_TOT);

    prep_weights<<<512, 256, 0, stream>>>(lm_W, gnn_W, W1S, W2S);
    fused<<<GRID, BLOCK, LDS_TOT, stream>>>(lm, gnn, ngn, lm_b, gnn_b,
                                            (const char*)W1S, (const char*)W2S, partials);
    finalize<<<1, 256, 0, stream>>>(partials, (float*)d_out);
}

// Round 12
// 209.198 us; speedup vs baseline: 1.4155x; 1.0233x over previous
//
#include <hip/hip_runtime.h>
#include <hip/hip_bf16.h>
#include <stdint.h>

#define NROWS 131072
#define LMD   1024
#define GNND  200
#define HD    128
#define BLOCK 256
#define MTILE 64
#define NBLK  (NROWS/MTILE)    // 2048
#define WCH   16384            // W chunk bytes (128 h x 64 k bf16)

typedef __attribute__((ext_vector_type(4))) float  f32x4;
typedef __attribute__((ext_vector_type(8))) short  bf16x8;

#define GLDS(SRC, DST) __builtin_amdgcn_global_load_lds( \
    (const __attribute__((address_space(1))) unsigned int*)(SRC), \
    (__attribute__((address_space(3))) unsigned int*)(DST), 16, 0, 0)
#define SCHED0  __builtin_amdgcn_sched_barrier(0)
#define BAR     __builtin_amdgcn_s_barrier()
#define VMW(N)  asm volatile("s_waitcnt vmcnt(" #N ")" ::: "memory")

__device__ __forceinline__ short f2bf(float x) {
    union { __hip_bfloat16 h; short s; } u;
    u.h = __float2bfloat16(x);
    return u.s;
}

__device__ __forceinline__ bf16x8 cvt8(f32x4 a, f32x4 b) {
    bf16x8 r;
    r[0]=f2bf(a[0]); r[1]=f2bf(a[1]); r[2]=f2bf(a[2]); r[3]=f2bf(a[3]);
    r[4]=f2bf(b[0]); r[5]=f2bf(b[1]); r[6]=f2bf(b[2]); r[7]=f2bf(b[3]);
    return r;
}

__device__ __forceinline__ float red16(float v) {
    #pragma unroll
    for (int m=1; m<16; m<<=1) v += __shfl_xor(v, m, 16);
    return v;
}

// ---- prep: K=64 chunk-major, swizzle-baked W panels ----
// W1S[ch][row][e] = bf16(lm_W[kk][row]), kk = ch*64 + (e ^ ((row&7)*8))
__global__ void prep_weights(const float* __restrict__ lm_W,
                             const float* __restrict__ gnn_W,
                             short* __restrict__ W1S, short* __restrict__ W2S)
{
    int idx = blockIdx.x*BLOCK + threadIdx.x;     // 512*256 = 131072 = 16 chunks * 8192 shorts
    int row = (idx >> 6) & 127;
    int e   = idx & 63;
    int kk  = (idx >> 13)*64 + (e ^ ((row & 7)*8));
    W1S[idx] = f2bf(lm_W[(long)kk*HD + row]);
    if (idx < 4*8192) {
        W2S[idx] = (kk < GNND) ? f2bf(gnn_W[(long)kk*HD + row]) : (short)0;
    }
}

__global__ __launch_bounds__(BLOCK) void fused(
    const float* __restrict__ lm,  const float* __restrict__ gnn,
    const float* __restrict__ ngn,
    const float* __restrict__ lm_b, const float* __restrict__ gnn_b,
    const char* __restrict__ W1S,  const char* __restrict__ W2S,
    float* __restrict__ partials)
{
    __shared__ short lbuf[4*8192];      // 64 KB: W bufs b0..b3
    __shared__ char  pdump[1024];       // prefetch dump (never read)
    __shared__ float sp[4], sn[4];

    const int tid  = threadIdx.x;
    const int lane = tid & 63;
    const int win  = tid >> 6;
    const int col  = lane & 15;
    const int g    = lane >> 4;
    const int wq   = win*4096 + lane*16;           // wave's staging quarter
    const long R0  = (long)blockIdx.x * MTILE;
    const long row = R0 + win*16 + col;
    const int rotg = blockIdx.x & 7;               // k-phase rotation (kept from R9)

    const char* aL = (const char*)lm  + row*(LMD*4L)  + g*32;
    const char* aG = (const char*)gnn + row*(GNND*4L) + g*32;
    const char* aN = (const char*)ngn + row*(GNND*4L) + g*32;
    const char* bLblk = (const char*)lm  + R0*(LMD*4L);
    const char* bGblk = (const char*)gnn + R0*(GNND*4L);
    const char* bNblk = (const char*)ngn + R0*(GNND*4L);
    const char* clampG   = (const char*)gnn + (size_t)NROWS*GNND*4 - 16;
    const char* clampN   = (const char*)ngn + (size_t)NROWS*GNND*4 - 16;
    const char* clampG64 = (const char*)gnn + (size_t)NROWS*GNND*4 - 64;
    const char* clampN64 = (const char*)ngn + (size_t)NROWS*GNND*4 - 64;

    const float CC   = 1.0f / 11008.0f;
    const float LOGC = -9.3063777f;                // log(1/11008)
    const f32x4 fz = {0.f,0.f,0.f,0.f};

    // rotated lm A-group byte offset
    auto LOFF = [&](int p)->int { return ((p + rotg) & 7) * 512; };
    // rotated W source for physical chunk p
    auto WSRC = [&](int p)->const char* {
        if (p < 16) {
            int lc = 2*(((p >> 1) + rotg) & 7) + (p & 1);
            return W1S + (size_t)lc*WCH;
        }
        return W2S + (size_t)(p - 16)*WCH;
    };

    auto ISSUEW = [&](const char* ws, int b) {
        const char* s = ws + wq;
        char* d = (char*)lbuf + (size_t)b*WCH + wq;
        #pragma unroll
        for (int i=0;i<4;i++) GLDS(s + i*1024, d + i*1024);
    };
    auto LOADG = [&](const char* base, int off, const char* cl, f32x4 (&S)[8]) {
        #pragma unroll
        for (int j=0;j<4;j++) {
            const char* p0 = base + off + j*128;
            const char* p1 = p0 + 16;
            if (cl) { if (p0 > cl) p0 = cl;  if (p1 > cl) p1 = cl; }
            S[2*j]   = *(const f32x4*)p0;
            S[2*j+1] = *(const f32x4*)p1;
        }
    };
    // fire-and-forget L2 prefetch of A-group x (one load per 64B line, 2/thread)
    auto PREF = [&](int x) {
        const char* base; long rowB; const char* cl = nullptr; long off;
        if (x < 8)       { base = bLblk; rowB = LMD*4L;  off = LOFF(x); }
        else if (x < 10) { base = bGblk; rowB = GNND*4L; off = (long)(x-8)*512;  cl = clampG64; }
        else             { base = bNblk; rowB = GNND*4L; off = (long)(x-10)*512; cl = clampN64; }
        #pragma unroll
        for (int i=0;i<2;i++) {
            int u = i*BLOCK + tid;                 // 512 lines: row=u>>3, line=u&7
            const char* src = base + (long)(u >> 3)*rowB + off + (long)(u & 7)*64;
            if (cl && src > cl) src = cl;
            GLDS(src, pdump);
        }
    };
    auto COMP = [&](int c, int half, f32x4 (&S)[8], f32x4 (&acc)[8]) {
        const short* wb = lbuf + (c & 3)*8192 + col*64;
        const int sw = (col & 7)*8;
        #pragma unroll
        for (int ks=0; ks<2; ++ks) {
            bf16x8 af = cvt8(S[half*4 + 2*ks], S[half*4 + 2*ks + 1]);
            const short* cb = wb + ((ks*32 + g*8) ^ sw);
            #pragma unroll
            for (int t=0;t<8;t++) {
                bf16x8 wf = *(const bf16x8*)(cb + t*1024);
                acc[t] = __builtin_amdgcn_mfma_f32_16x16x32_bf16(af, wf, acc[t], 0,0,0);
            }
        }
    };

    f32x4 accL[8], accG[8];
    #pragma unroll
    for (int t=0;t<8;t++) accL[t] = fz;
    f32x4 SA[8], SB[8];
    float pos_acc = 0.f, neg_acc = 0.f;

    // ---- prologue: biases, W0-2, Agrp0-1, P(2) ----
    float bl[8], bg[8];
    #pragma unroll
    for (int t=0;t<8;t++) bl[t] = lm_b[t*16+col];
    #pragma unroll
    for (int t=0;t<8;t++) bg[t] = gnn_b[t*16+col];
    SCHED0;
    ISSUEW(WSRC(0), 0); ISSUEW(WSRC(1), 1); ISSUEW(WSRC(2), 2);
    LOADG(aL, LOFF(0), nullptr, SA);
    LOADG(aL, LOFF(1), nullptr, SB);
    PREF(2);
    SCHED0; VMW(26); SCHED0; BAR; SCHED0;
    #pragma unroll
    for (int t=0;t<8;t++) { asm volatile("" : "+v"(bl[t])); asm volatile("" : "+v"(bg[t])); }

    // ---- lm phase: groups 0..7 (chunks 0..15) ----
    #pragma unroll
    for (int gg=0; gg<8; ++gg) {
        f32x4 (&S)[8] = (gg & 1) ? SB : SA;
        // even chunk 2gg
        ISSUEW(WSRC(2*gg+3), (2*gg+3) & 3);
        SCHED0;
        COMP(2*gg, 0, S, accL);
        SCHED0; VMW(18); SCHED0; BAR; SCHED0;
        // odd chunk 2gg+1
        ISSUEW(WSRC(2*gg+4), (2*gg+4) & 3);
        SCHED0;
        COMP(2*gg+1, 1, S, accL);
        SCHED0;
        if (gg < 6)       LOADG(aL, LOFF(gg+2), nullptr, S);   // grp gg+2 (lm, rotated)
        else if (gg == 6) LOADG(aG,   0, clampG, S);           // grp 8 (gnn)
        else              LOADG(aG, 512, clampG, S);           // grp 9 (gnn)
        PREF(gg+3);                                            // grp gg+3, 1 slot ahead
        SCHED0; VMW(28); SCHED0; BAR; SCHED0;
    }

    // lm bias epilogue
    #pragma unroll
    for (int t=0;t<8;t++) {
        #pragma unroll
        for (int r=0;r<4;r++) accL[t][r] += bl[t];
    }
    #pragma unroll
    for (int t=0;t<8;t++) accG[t] = fz;

    // ---- pos phase: chunks 16..19 ----
    ISSUEW(WSRC(19), 3);
    PREF(11);
    SCHED0;
    COMP(16, 0, SA, accG);
    SCHED0; VMW(20); SCHED0; BAR; SCHED0;

    COMP(17, 1, SA, accG);
    SCHED0;
    LOADG(aN, 0, clampN, SA);                                  // grp 10 (ngn)
    SCHED0; VMW(24); SCHED0; BAR; SCHED0;

    COMP(18, 0, SB, accG);
    SCHED0; VMW(10); SCHED0; BAR; SCHED0;

    COMP(19, 1, SB, accG);
    SCHED0;
    LOADG(aN, 512, clampN, SB);                                // grp 11 (ngn)
    SCHED0;
    // barrier-free from here: W2 resident in b0..b3

    // pos epilogue
    #pragma unroll
    for (int r=0;r<4;r++) {
        float lg=0.f, ll=0.f, gg2=0.f;
        #pragma unroll
        for (int t=0;t<8;t++) {
            float lv=accL[t][r], gv=accG[t][r]+bg[t];
            lg += lv*gv; ll += lv*lv; gg2 += gv*gv;
        }
        lg=red16(lg); ll=red16(ll); gg2=red16(gg2);
        float d  = lg * rsqrtf(ll*gg2);
        float pi = d - logf(expf(d)+CC);     // log(ratio)
        if (col==0) pos_acc += pi;
    }
    #pragma unroll
    for (int t=0;t<8;t++) accG[t] = fz;

    // ---- neg phase: chunks 20..23 (barrier-free, desynced) ----
    COMP(20, 0, SA, accG);
    COMP(21, 1, SA, accG);
    COMP(22, 0, SB, accG);
    COMP(23, 1, SB, accG);

    // neg epilogue
    #pragma unroll
    for (int r=0;r<4;r++) {
        float ln=0.f, nn=0.f, ll=0.f;
        #pragma unroll
        for (int t=0;t<8;t++) {
            float lv=accL[t][r], nv=accG[t][r]+bg[t];
            ln += lv*nv; nn += nv*nv; ll += lv*lv;
        }
        ln=red16(ln); nn=red16(nn); ll=red16(ll);
        float d  = ln * rsqrtf(ll*nn);
        float ni = LOGC - logf(expf(d)+CC);  // log(1-ratio)
        if (col==0) neg_acc += ni;
    }

    // ---- wave + block reduce ----
    #pragma unroll
    for (int m=1;m<64;m<<=1) {
        pos_acc += __shfl_xor(pos_acc, m, 64);
        neg_acc += __shfl_xor(neg_acc, m, 64);
    }
    if (lane==0) { sp[win]=pos_acc; sn[win]=neg_acc; }
    __syncthreads();
    if (tid==0) {
        float p=0.f,n=0.f;
        #pragma unroll
        for (int w=0;w<4;w++){ p+=sp[w]; n+=sn[w]; }
        partials[blockIdx.x*2]   = p;
        partials[blockIdx.x*2+1] = n;
    }
}

__global__ void finalize(const float* __restrict__ partials, float* __restrict__ out)
{
    __shared__ float sp[BLOCK], sn[BLOCK];
    float p=0.f, n=0.f;
    for (int i=threadIdx.x; i<NBLK; i+=BLOCK) { p += partials[2*i]; n += partials[2*i+1]; }
    sp[threadIdx.x]=p; sn[threadIdx.x]=n;
    __syncthreads();
    for (int s=BLOCK/2; s>0; s>>=1) {
        if (threadIdx.x < s) { sp[threadIdx.x]+=sp[threadIdx.x+s]; sn[threadIdx.x]+=sn[threadIdx.x+s]; }
        __syncthreads();
    }
    if (threadIdx.x==0) out[0] = -(sp[0]+sn[0]) / (float)NROWS;
}

extern "C" void kernel_launch(void* const* d_in, const int* in_sizes, int n_in,
                              void* d_out, int out_size, void* d_ws, size_t ws_size,
                              hipStream_t stream)
{
    const float* lm    = (const float*)d_in[0];
    const float* gnn   = (const float*)d_in[1];
    const float* ngn   = (const float*)d_in[2];
    const float* lm_W  = (const float*)d_in[3];
    const float* lm_b  = (const float*)d_in[4];
    const float* gnn_W = (const float*)d_in[5];
    const float* gnn_b = (const float*)d_in[6];

    short* W1S = (short*)d_ws;                                   // 16*16384 = 262144 B
    short* W2S = (short*)((char*)d_ws + 262144);                 //  4*16384 =  65536 B
    float* partials = (float*)((char*)d_ws + 262144 + 65536);    // 16 KB

    prep_weights<<<512, BLOCK, 0, stream>>>(lm_W, gnn_W, W1S, W2S);
    fused<<<NBLK, BLOCK, 0, stream>>>(lm, gnn, ngn, lm_b, gnn_b,
                                      (const char*)W1S, (const char*)W2S, partials);
    finalize<<<1, BLOCK, 0, stream>>>(partials, (float*)d_out);
}